// Round 1
// baseline (3129.656 us; speedup 1.0000x reference)
//
#include <hip/hip_runtime.h>
#include <math.h>

#define B_ 4
#define L_ 2048
#define D_ 1024
#define H_ 16
#define HD_ 64   // head dim

// ---------------------------------------------------------------------------
// Tiled fp32 SGEMM, C = [silu](A @ W).  A: MxK row-major, W: KxN row-major.
// 64x64 block tile, BK=32, 256 threads, 4x4 per thread.
// As pad 65: staging write (c*65+r)%32 -> 2-way (free); compute reads broadcast.
// Bs pad 68: compute read (kk*68 + 4tx+j) -> 2-way (free), 16B-aligned rows.
// ---------------------------------------------------------------------------
template <int DO_SILU>
__global__ __launch_bounds__(256) void sgemm_silu(const float* __restrict__ A,
                                                  const float* __restrict__ W,
                                                  float* __restrict__ C,
                                                  int M, int N, int K) {
  __shared__ float As[32][65];  // [k][m]
  __shared__ float Bs[32][68];  // [k][n]
  const int tid = threadIdx.x;
  const int tx = tid & 15, ty = tid >> 4;
  const int m0 = blockIdx.y * 64, n0 = blockIdx.x * 64;
  float acc[4][4] = {};
  for (int k0 = 0; k0 < K; k0 += 32) {
#pragma unroll
    for (int i = 0; i < 8; ++i) {
      int e = tid + i * 256;
      int r = e >> 5, c = e & 31;  // r<64 (m), c<32 (k)
      As[c][r] = A[(size_t)(m0 + r) * K + (k0 + c)];
    }
#pragma unroll
    for (int i = 0; i < 8; ++i) {
      int e = tid + i * 256;
      int r = e >> 6, c = e & 63;  // r<32 (k), c<64 (n)
      Bs[r][c] = W[(size_t)(k0 + r) * N + (n0 + c)];
    }
    __syncthreads();
#pragma unroll
    for (int kk = 0; kk < 32; ++kk) {
      float a[4], b[4];
#pragma unroll
      for (int i = 0; i < 4; ++i) a[i] = As[kk][ty * 4 + i];
#pragma unroll
      for (int j = 0; j < 4; ++j) b[j] = Bs[kk][tx * 4 + j];
#pragma unroll
      for (int i = 0; i < 4; ++i)
#pragma unroll
        for (int j = 0; j < 4; ++j) acc[i][j] = fmaf(a[i], b[j], acc[i][j]);
    }
    __syncthreads();
  }
#pragma unroll
  for (int i = 0; i < 4; ++i)
#pragma unroll
    for (int j = 0; j < 4; ++j) {
      float v = acc[i][j];
      if (DO_SILU) v = v / (1.0f + __expf(-v));
      C[(size_t)(m0 + ty * 4 + i) * N + (n0 + tx * 4 + j)] = v;
    }
}

// ---------------------------------------------------------------------------
// In-place RoPE on q (cols 0..1023) and k (cols 1024..2047) of qkuv.
// One thread per (b, l, h, j<32) pair; pairs (j, j+32) within each 64-dim head.
// new[j]    = x[j]*cos - x[j+32]*sin
// new[j+32] = x[j+32]*cos + x[j]*sin,  angle = l * 10000^(-j/32)
// ---------------------------------------------------------------------------
__global__ __launch_bounds__(256) void rope_kernel(float* __restrict__ qkuv) {
  int idx = blockIdx.x * 256 + threadIdx.x;  // B*L*H*32 total
  int j = idx & 31;
  int h = (idx >> 5) & (H_ - 1);
  int l = (idx >> 9) & (L_ - 1);
  int b = idx >> 20;
  // inv_freq = 10000^(-j/32) = exp(-j * ln(10000)/32)
  float inv = expf(-(float)j * (9.2103403719761836f / 32.0f));
  float ang = (float)l * inv;
  float c = cosf(ang), s = sinf(ang);
  float* base = qkuv + ((size_t)(b * L_ + l) * (4 * D_)) + h * HD_ + j;
  float q0 = base[0], q1 = base[32];
  base[0] = q0 * c - q1 * s;
  base[32] = q1 * c + q0 * s;
  float k0 = base[D_], k1 = base[D_ + 32];
  base[D_] = k0 * c - k1 * s;
  base[D_ + 32] = k1 * c + k0 * s;
}

// ---------------------------------------------------------------------------
// Fused attention: per block = one (b,h) and 64 query rows.
// Streams 64-wide key tiles: S = QK^T/8 + cm*cb -> silu -> *mask, O += S@V.
// (No softmax normalization in this model -> plain accumulation is exact.)
// Epilogue: LayerNorm over head dim (64), *gamma +beta, gate by u.
// ---------------------------------------------------------------------------
__global__ __launch_bounds__(256) void attn_kernel(
    const float* __restrict__ qkuv, const float* __restrict__ amask,
    const float* __restrict__ cmask, const float* __restrict__ cbias,
    const float* __restrict__ gamma, const float* __restrict__ beta,
    float* __restrict__ attng) {
  __shared__ float Qs[64][65];
  __shared__ float Ks[64][65];
  __shared__ float Vs[64][65];
  __shared__ float Ss[64][68];
  __shared__ float muA[64], rsA[64];
  const int tid = threadIdx.x;
  const int tx = tid & 15, ty = tid >> 4;
  const int b = blockIdx.y >> 4, h = blockIdx.y & 15;
  const int l0 = blockIdx.x * 64;
  const float cb = cbias[h];

  // Stage Q tile (RoPE already applied in-place).
#pragma unroll
  for (int i = 0; i < 16; ++i) {
    int e = tid + i * 256;
    int r = e >> 6, c = e & 63;
    Qs[r][c] = qkuv[((size_t)(b * L_ + l0 + r)) * (4 * D_) + h * HD_ + c];
  }

  float acc[4][4] = {};
  for (int m0 = 0; m0 < L_; m0 += 64) {
    __syncthreads();  // protect prev-iter Ss/Vs reads (and first-iter Q store)
#pragma unroll
    for (int i = 0; i < 16; ++i) {
      int e = tid + i * 256;
      int r = e >> 6, c = e & 63;
      size_t g = ((size_t)(b * L_ + m0 + r)) * (4 * D_) + h * HD_ + c;
      Ks[r][c] = qkuv[g + D_];      // k quarter
      Vs[r][c] = qkuv[g + 2 * D_];  // v quarter
    }
    __syncthreads();

    // S tile: 4x4 per thread over k=0..63
    float s[4][4] = {};
#pragma unroll
    for (int k = 0; k < 64; ++k) {
      float a[4], bb[4];
#pragma unroll
      for (int i = 0; i < 4; ++i) a[i] = Qs[ty * 4 + i][k];
#pragma unroll
      for (int j = 0; j < 4; ++j) bb[j] = Ks[tx * 4 + j][k];
#pragma unroll
      for (int i = 0; i < 4; ++i)
#pragma unroll
        for (int j = 0; j < 4; ++j) s[i][j] = fmaf(a[i], bb[j], s[i][j]);
    }
    // bias + silu + mask, write to Ss
#pragma unroll
    for (int i = 0; i < 4; ++i)
#pragma unroll
      for (int j = 0; j < 4; ++j) {
        int row = l0 + ty * 4 + i;  // query pos
        int col = m0 + tx * 4 + j;  // key pos
        float v = s[i][j] * 0.125f + cmask[b * L_ + col] * cb;
        v = v / (1.0f + __expf(-v));
        v *= amask[((size_t)(b * L_ + row)) * L_ + col];
        Ss[ty * 4 + i][tx * 4 + j] = v;
      }
    __syncthreads();

    // O += Ss @ Vs
#pragma unroll
    for (int mm = 0; mm < 64; ++mm) {
      float ss[4], vv[4];
#pragma unroll
      for (int i = 0; i < 4; ++i) ss[i] = Ss[ty * 4 + i][mm];
#pragma unroll
      for (int j = 0; j < 4; ++j) vv[j] = Vs[mm][tx * 4 + j];
#pragma unroll
      for (int i = 0; i < 4; ++i)
#pragma unroll
        for (int j = 0; j < 4; ++j) acc[i][j] = fmaf(ss[i], vv[j], acc[i][j]);
    }
  }

  // LayerNorm over head dim + u-gate
  __syncthreads();
#pragma unroll
  for (int i = 0; i < 4; ++i)
#pragma unroll
    for (int j = 0; j < 4; ++j) Ss[ty * 4 + i][tx * 4 + j] = acc[i][j];
  __syncthreads();
  if (tid < 64) {
    float sum = 0.f, sq = 0.f;
#pragma unroll
    for (int c = 0; c < 64; ++c) {
      float v = Ss[tid][c];
      sum += v;
      sq += v * v;
    }
    float mu = sum * (1.0f / 64.0f);
    float var = sq * (1.0f / 64.0f) - mu * mu;
    muA[tid] = mu;
    rsA[tid] = rsqrtf(var + 1e-5f);
  }
  __syncthreads();
#pragma unroll
  for (int i = 0; i < 16; ++i) {
    int e = tid + i * 256;
    int r = e >> 6, c = e & 63;
    float v = (Ss[r][c] - muA[r]) * rsA[r] * gamma[c] + beta[c];
    float u = qkuv[((size_t)(b * L_ + l0 + r)) * (4 * D_) + 3 * D_ + h * HD_ + c];
    attng[((size_t)(b * L_ + l0 + r)) * D_ + h * HD_ + c] = v * u;
  }
}

extern "C" void kernel_launch(void* const* d_in, const int* in_sizes, int n_in,
                              void* d_out, int out_size, void* d_ws, size_t ws_size,
                              hipStream_t stream) {
  const float* x = (const float*)d_in[0];
  const float* amask = (const float*)d_in[1];
  const float* cmask = (const float*)d_in[2];
  const float* Wqkuv = (const float*)d_in[3];
  const float* Wout = (const float*)d_in[4];
  const float* gamma = (const float*)d_in[5];
  const float* beta = (const float*)d_in[6];
  const float* cbias = (const float*)d_in[7];
  float* out = (float*)d_out;

  // Workspace: qkuv (B*L*4D fp32 = 128 MB) + gated attn out (B*L*D = 32 MB)
  float* qkuv = (float*)d_ws;
  float* attng = qkuv + (size_t)B_ * L_ * 4 * D_;

  // 1) qkuv = silu(x @ Wqkuv)   M=8192 N=4096 K=1024
  sgemm_silu<1><<<dim3((4 * D_) / 64, (B_ * L_) / 64), 256, 0, stream>>>(
      x, Wqkuv, qkuv, B_ * L_, 4 * D_, D_);
  // 2) RoPE in-place on q,k quarters
  rope_kernel<<<(B_ * L_ * H_ * 32) / 256, 256, 0, stream>>>(qkuv);
  // 3) fused attention + LN + u-gate
  attn_kernel<<<dim3(L_ / 64, B_ * H_), 256, 0, stream>>>(
      qkuv, amask, cmask, cbias, gamma, beta, attng);
  // 4) out = attng @ Wout       M=8192 N=1024 K=1024
  sgemm_silu<0><<<dim3(D_ / 64, (B_ * L_) / 64), 256, 0, stream>>>(
      attng, Wout, out, B_ * L_, D_, D_);
}

// Round 3
// 787.705 us; speedup vs baseline: 3.9731x; 3.9731x over previous
//
#include <hip/hip_runtime.h>
#include <math.h>

#define B_ 4
#define L_ 2048
#define D_ 1024
#define H_ 16

typedef __attribute__((ext_vector_type(4))) float f32x4;
typedef __attribute__((ext_vector_type(2))) float f32x2;
typedef __attribute__((ext_vector_type(8))) short s16x8;
typedef __attribute__((ext_vector_type(4))) unsigned short u16x4;

__device__ __forceinline__ unsigned short f2bf(float f) {
  unsigned int u = __float_as_uint(f);
  u += 0x7fffu + ((u >> 16) & 1u);  // RNE
  return (unsigned short)(u >> 16);
}
__device__ __forceinline__ float b2f(unsigned short s) {
  return __uint_as_float(((unsigned int)s) << 16);
}

// ---------------------------------------------------------------------------
// fp32 -> bf16 elementwise (x)
// ---------------------------------------------------------------------------
__global__ __launch_bounds__(256) void conv_x(const float* __restrict__ x,
                                              unsigned short* __restrict__ xb, int n4) {
  int i = blockIdx.x * 256 + threadIdx.x;
  if (i < n4) {
    f32x4 v = *(const f32x4*)(x + (size_t)i * 4);
    u16x4 o;
#pragma unroll
    for (int j = 0; j < 4; ++j) o[j] = f2bf(v[j]);
    *(u16x4*)(xb + (size_t)i * 4) = o;
  }
}

// ---------------------------------------------------------------------------
// W[K][N] fp32 -> Wt[N][K] bf16 (LDS tile transpose)
// ---------------------------------------------------------------------------
__global__ __launch_bounds__(256) void trans_w(const float* __restrict__ W,
                                               unsigned short* __restrict__ Wt,
                                               int K, int N) {
  __shared__ float T[64][65];
  const int k0 = blockIdx.y * 64, n0 = blockIdx.x * 64;
  const int tid = threadIdx.x;
#pragma unroll
  for (int i = 0; i < 16; ++i) {
    int e = tid + i * 256;
    int r = e >> 6, c = e & 63;
    T[r][c] = W[(size_t)(k0 + r) * N + n0 + c];
  }
  __syncthreads();
#pragma unroll
  for (int i = 0; i < 16; ++i) {
    int e = tid + i * 256;
    int r = e >> 6, c = e & 63;
    Wt[(size_t)(n0 + r) * K + k0 + c] = f2bf(T[c][r]);
  }
}

// ---------------------------------------------------------------------------
// RoPE cos/sin table [L][32] (shared across all heads)
// ---------------------------------------------------------------------------
__global__ __launch_bounds__(256) void rope_tab(f32x2* __restrict__ tab) {
  int i = blockIdx.x * 256 + threadIdx.x;  // L_*32
  int l = i >> 5, j = i & 31;
  float inv = expf(-(float)j * (9.210340371976184f / 32.0f));  // 10000^(-j/32)
  float ang = (float)l * inv;
  f32x2 cs;
  cs[0] = cosf(ang);
  cs[1] = sinf(ang);
  tab[i] = cs;
}

// ---------------------------------------------------------------------------
// bf16 MFMA GEMM: C = [silu](A @ Bt^T). A:[M][K] bf16, Bt:[N][K] bf16.
// 128x128 tile, BK=32, 256 threads = 4 waves (2x2 of 64x64).
// MODE 1: bf16 out + silu (GEMM1 -> qkuv). MODE 0: fp32 out (GEMM2 -> d_out).
// Frag layouts (verified, learn_hip m89/m91/m97):
//   a[j] = A[m=lane&15][k=quad*8+j]; b[j] = Bt[n=lane&15][k=quad*8+j]
//   C/D: row = quad*4+reg, col = lane&15
// LDS rows padded to 40 shorts (80 B) -> balanced banks for ds_read_b128.
// Staging tile: 128 rows x 32 cols = 512 s16x8 chunks -> r=ch>>2, c=ch&3.
// ---------------------------------------------------------------------------
template <int MODE>
__global__ __launch_bounds__(256) void gemm_bf16(const unsigned short* __restrict__ A,
                                                 const unsigned short* __restrict__ Bt,
                                                 void* __restrict__ Cp,
                                                 int M, int N, int K) {
  alignas(16) __shared__ unsigned short As[128][40];
  alignas(16) __shared__ unsigned short Bs[128][40];
  const int tid = threadIdx.x;
  const int lane = tid & 63, w = tid >> 6;
  const int quad = lane >> 4, l15 = lane & 15;
  const int wr = w >> 1, wc = w & 1;
  const int m0 = blockIdx.y * 128, n0 = blockIdx.x * 128;
  f32x4 acc[4][4] = {};
  for (int k0 = 0; k0 < K; k0 += 32) {
#pragma unroll
    for (int i = 0; i < 2; ++i) {
      int ch = tid + i * 256;
      int r = ch >> 2, c = ch & 3;  // 128 rows x 4 chunks (32 cols)
      *(s16x8*)&As[r][c * 8] = *(const s16x8*)(A + (size_t)(m0 + r) * K + k0 + c * 8);
      *(s16x8*)&Bs[r][c * 8] = *(const s16x8*)(Bt + (size_t)(n0 + r) * K + k0 + c * 8);
    }
    __syncthreads();
    s16x8 af[4], bf[4];
#pragma unroll
    for (int mi = 0; mi < 4; ++mi) af[mi] = *(const s16x8*)&As[wr * 64 + mi * 16 + l15][quad * 8];
#pragma unroll
    for (int nj = 0; nj < 4; ++nj) bf[nj] = *(const s16x8*)&Bs[wc * 64 + nj * 16 + l15][quad * 8];
#pragma unroll
    for (int mi = 0; mi < 4; ++mi)
#pragma unroll
      for (int nj = 0; nj < 4; ++nj)
        acc[mi][nj] = __builtin_amdgcn_mfma_f32_16x16x32_bf16(af[mi], bf[nj], acc[mi][nj], 0, 0, 0);
    __syncthreads();
  }
#pragma unroll
  for (int mi = 0; mi < 4; ++mi)
#pragma unroll
    for (int nj = 0; nj < 4; ++nj)
#pragma unroll
      for (int reg = 0; reg < 4; ++reg) {
        int rg = m0 + wr * 64 + mi * 16 + quad * 4 + reg;
        int cg = n0 + wc * 64 + nj * 16 + l15;
        float v = acc[mi][nj][reg];
        if (MODE == 1) {
          v = v / (1.0f + __expf(-v));  // silu
          ((unsigned short*)Cp)[(size_t)rg * N + cg] = f2bf(v);
        } else {
          ((float*)Cp)[(size_t)rg * N + cg] = v;
        }
      }
}

// ---------------------------------------------------------------------------
// In-place RoPE on q,k quarters of qkuv_bf + build v_t[bh][64 d][L] bf16.
// Block: one (b,h), 64 seq rows.
// ---------------------------------------------------------------------------
__global__ __launch_bounds__(256) void rope_conv(unsigned short* __restrict__ qk,
                                                 unsigned short* __restrict__ vt,
                                                 const f32x2* __restrict__ tab) {
  alignas(16) __shared__ unsigned short Vsh[64][72];
  const int tid = threadIdx.x;
  const int bh = blockIdx.y, b = bh >> 4, h = bh & 15;
  const int l0 = blockIdx.x * 64;
  // rope q,k in place: pairs (j, j+32) within head
#pragma unroll
  for (int i = 0; i < 2; ++i) {
    int p = tid + i * 256;
    int row = p >> 3, c4 = p & 7;  // c4*4 in [0,32)
    int l = l0 + row;
    size_t base = (size_t)(b * L_ + l) * 4096 + h * 64 + c4 * 4;
#pragma unroll
    for (int t = 0; t < 2; ++t) {  // 0: q, 1: k
      size_t o = base + (size_t)t * 1024;
      u16x4 lo = *(u16x4*)(qk + o);
      u16x4 hi = *(u16x4*)(qk + o + 32);
      u16x4 nlo, nhi;
#pragma unroll
      for (int jj = 0; jj < 4; ++jj) {
        f32x2 cs = tab[l * 32 + c4 * 4 + jj];
        float fl = b2f(lo[jj]), fh = b2f(hi[jj]);
        nlo[jj] = f2bf(fl * cs[0] - fh * cs[1]);
        nhi[jj] = f2bf(fh * cs[0] + fl * cs[1]);
      }
      *(u16x4*)(qk + o) = nlo;
      *(u16x4*)(qk + o + 32) = nhi;
    }
  }
  // v quarter: transpose 64x64 tile -> v_t[d][l]
#pragma unroll
  for (int i = 0; i < 2; ++i) {
    int ch = tid + i * 256;
    int row = ch >> 3, c8 = ch & 7;
    *(s16x8*)&Vsh[row][c8 * 8] =
        *(const s16x8*)(qk + (size_t)(b * L_ + l0 + row) * 4096 + 2048 + h * 64 + c8 * 8);
  }
  __syncthreads();
#pragma unroll
  for (int i = 0; i < 2; ++i) {
    int ch = tid + i * 256;
    int drow = ch >> 3, c8 = ch & 7;
    s16x8 o;
#pragma unroll
    for (int jj = 0; jj < 8; ++jj) o[jj] = (short)Vsh[c8 * 8 + jj][drow];
    *(s16x8*)(vt + (size_t)(bh * 64 + drow) * 2048 + l0 + c8 * 8) = o;
  }
}

// ---------------------------------------------------------------------------
// Fused MFMA attention. Block = one (b,h), 64 query rows; wave w owns 16 rows.
// Per 64-key tile: S=QK^T (MFMA) -> scale+bias+silu+mask -> P (LDS, own rows,
// no barrier needed) -> O += P@V (MFMA, V pre-transposed so b-frags are b128).
// Staging tiles here are 64 rows x 64 cols = 512 s16x8 chunks -> r=ch>>3,
// c=ch&7 (round-2 bug: used the GEMM's 128x32 mapping -> LDS overflow + OOB).
// Epilogue: LN over d=64 via shfl-xor (rows live in one 16-lane group), u-gate.
// No softmax normalization in this model -> plain accumulation is exact.
// ---------------------------------------------------------------------------
__global__ __launch_bounds__(256) void attn_mfma(
    const unsigned short* __restrict__ qk, const unsigned short* __restrict__ vt,
    const float* __restrict__ amask, const float* __restrict__ cmask,
    const float* __restrict__ cbias, const float* __restrict__ gamma,
    const float* __restrict__ beta, unsigned short* __restrict__ attng) {
  alignas(16) __shared__ unsigned short Qs[64][72];
  alignas(16) __shared__ unsigned short Ks[64][72];
  alignas(16) __shared__ unsigned short Vts[64][72];
  alignas(16) __shared__ unsigned short Ps[64][72];
  const int tid = threadIdx.x;
  const int lane = tid & 63, w = tid >> 6;
  const int quad = lane >> 4, l15 = lane & 15;
  const int bh = blockIdx.y, b = bh >> 4, h = bh & 15;
  const int l0 = blockIdx.x * 64;
  const float cb = cbias[h];
  float ga[4], be[4];
#pragma unroll
  for (int nt = 0; nt < 4; ++nt) {
    ga[nt] = gamma[nt * 16 + l15];
    be[nt] = beta[nt * 16 + l15];
  }

#pragma unroll
  for (int i = 0; i < 2; ++i) {  // stage Q once: 64 rows x 8 chunks
    int ch = tid + i * 256;
    int r = ch >> 3, c = ch & 7;
    *(s16x8*)&Qs[r][c * 8] = *(const s16x8*)(qk + (size_t)(b * L_ + l0 + r) * 4096 + h * 64 + c * 8);
  }

  f32x4 oacc[4] = {};
  for (int m0 = 0; m0 < L_; m0 += 64) {
    __syncthreads();  // Q ready (iter0) / prev-iter Ks,Vts,Ps fully consumed
#pragma unroll
    for (int i = 0; i < 2; ++i) {
      int ch = tid + i * 256;
      int r = ch >> 3, c = ch & 7;  // 64 rows x 8 chunks
      *(s16x8*)&Ks[r][c * 8] =
          *(const s16x8*)(qk + (size_t)(b * L_ + m0 + r) * 4096 + 1024 + h * 64 + c * 8);
      *(s16x8*)&Vts[r][c * 8] = *(const s16x8*)(vt + (size_t)(bh * 64 + r) * 2048 + m0 + c * 8);
    }
    __syncthreads();

    f32x4 sacc[4] = {};
#pragma unroll
    for (int s = 0; s < 2; ++s) {
      s16x8 a = *(const s16x8*)&Qs[w * 16 + l15][s * 32 + quad * 8];
#pragma unroll
      for (int nt = 0; nt < 4; ++nt) {
        s16x8 bb = *(const s16x8*)&Ks[nt * 16 + l15][s * 32 + quad * 8];
        sacc[nt] = __builtin_amdgcn_mfma_f32_16x16x32_bf16(a, bb, sacc[nt], 0, 0, 0);
      }
    }
    // scale + conversion bias + silu + attn mask -> P (this wave's 16 rows)
#pragma unroll
    for (int nt = 0; nt < 4; ++nt) {
      float cm = cmask[(size_t)b * L_ + m0 + nt * 16 + l15];
#pragma unroll
      for (int reg = 0; reg < 4; ++reg) {
        int rl = quad * 4 + reg;
        int rowg = l0 + w * 16 + rl;
        int colg = m0 + nt * 16 + l15;
        float v = sacc[nt][reg] * 0.125f + cm * cb;
        v = v / (1.0f + __expf(-v));
        v *= amask[((size_t)b * L_ + rowg) * L_ + colg];
        Ps[w * 16 + rl][nt * 16 + l15] = f2bf(v);
      }
    }
    // O += P @ V  (wave reads only its own P rows; per-wave DS ops are
    // in-order, so no barrier needed between P write and P read)
#pragma unroll
    for (int s2 = 0; s2 < 2; ++s2) {
      s16x8 pa = *(const s16x8*)&Ps[w * 16 + l15][s2 * 32 + quad * 8];
#pragma unroll
      for (int nt = 0; nt < 4; ++nt) {
        s16x8 vb = *(const s16x8*)&Vts[nt * 16 + l15][s2 * 32 + quad * 8];
        oacc[nt] = __builtin_amdgcn_mfma_f32_16x16x32_bf16(pa, vb, oacc[nt], 0, 0, 0);
      }
    }
  }

  // LayerNorm over d=64: each lane's reg r is row quad*4+r; cols = 4 nt x 16 lanes
  float sm[4], sq[4], mu[4], rs[4];
#pragma unroll
  for (int reg = 0; reg < 4; ++reg) {
    float s1 = 0.f, s2 = 0.f;
#pragma unroll
    for (int nt = 0; nt < 4; ++nt) {
      float v = oacc[nt][reg];
      s1 += v;
      s2 += v * v;
    }
    sm[reg] = s1;
    sq[reg] = s2;
  }
#pragma unroll
  for (int m = 1; m < 16; m <<= 1) {
#pragma unroll
    for (int reg = 0; reg < 4; ++reg) {
      sm[reg] += __shfl_xor(sm[reg], m);
      sq[reg] += __shfl_xor(sq[reg], m);
    }
  }
#pragma unroll
  for (int reg = 0; reg < 4; ++reg) {
    mu[reg] = sm[reg] * (1.0f / 64.0f);
    float var = sq[reg] * (1.0f / 64.0f) - mu[reg] * mu[reg];
    rs[reg] = rsqrtf(var + 1e-5f);
  }
#pragma unroll
  for (int nt = 0; nt < 4; ++nt)
#pragma unroll
    for (int reg = 0; reg < 4; ++reg) {
      int rl = quad * 4 + reg;
      int rowg = l0 + w * 16 + rl;
      int colg = nt * 16 + l15;
      float v = (oacc[nt][reg] - mu[reg]) * rs[reg] * ga[nt] + be[nt];
      float u = b2f(qk[(size_t)(b * L_ + rowg) * 4096 + 3072 + h * 64 + colg]);
      attng[(size_t)(b * L_ + rowg) * 1024 + h * 64 + colg] = f2bf(v * u);
    }
}

extern "C" void kernel_launch(void* const* d_in, const int* in_sizes, int n_in,
                              void* d_out, int out_size, void* d_ws, size_t ws_size,
                              hipStream_t stream) {
  const float* x = (const float*)d_in[0];
  const float* amask = (const float*)d_in[1];
  const float* cmask = (const float*)d_in[2];
  const float* Wqkuv = (const float*)d_in[3];
  const float* Wout = (const float*)d_in[4];
  const float* gamma = (const float*)d_in[5];
  const float* beta = (const float*)d_in[6];
  const float* cbias = (const float*)d_in[7];
  float* out = (float*)d_out;

  char* ws = (char*)d_ws;
  unsigned short* qkuv_bf = (unsigned short*)ws;                    // 64 MB
  unsigned short* vt = (unsigned short*)(ws + ((size_t)64 << 20));  // 16 MB
  unsigned short* xbf = (unsigned short*)(ws + ((size_t)80 << 20));  // 16 MB
  unsigned short* Wt = (unsigned short*)(ws + ((size_t)96 << 20));   // 8 MB
  unsigned short* Wot = (unsigned short*)(ws + ((size_t)104 << 20)); // 2 MB
  unsigned short* attng = (unsigned short*)(ws + ((size_t)106 << 20)); // 16 MB
  f32x2* tab = (f32x2*)(ws + ((size_t)122 << 20));                   // 0.5 MB

  conv_x<<<8192, 256, 0, stream>>>(x, xbf, (B_ * L_ * D_) / 4);
  trans_w<<<dim3(4096 / 64, 1024 / 64), 256, 0, stream>>>(Wqkuv, Wt, 1024, 4096);
  trans_w<<<dim3(1024 / 64, 1024 / 64), 256, 0, stream>>>(Wout, Wot, 1024, 1024);
  rope_tab<<<(L_ * 32) / 256, 256, 0, stream>>>(tab);

  // qkuv = silu(x @ Wqkuv) in bf16
  gemm_bf16<1><<<dim3(4096 / 128, 8192 / 128), 256, 0, stream>>>(xbf, Wt, qkuv_bf,
                                                                 B_ * L_, 4 * D_, D_);
  rope_conv<<<dim3(L_ / 64, B_ * H_), 256, 0, stream>>>(qkuv_bf, vt, tab);
  attn_mfma<<<dim3(L_ / 64, B_ * H_), 256, 0, stream>>>(qkuv_bf, vt, amask, cmask, cbias,
                                                        gamma, beta, attng);
  // out = attng @ Wout
  gemm_bf16<0><<<dim3(1024 / 128, 8192 / 128), 256, 0, stream>>>(attng, Wot, out,
                                                                 B_ * L_, D_, D_);
}

// Round 4
// 529.496 us; speedup vs baseline: 5.9106x; 1.4877x over previous
//
#include <hip/hip_runtime.h>
#include <math.h>

#define B_ 4
#define L_ 2048
#define D_ 1024
#define H_ 16

typedef __attribute__((ext_vector_type(4))) float f32x4;
typedef __attribute__((ext_vector_type(2))) float f32x2;
typedef __attribute__((ext_vector_type(8))) short s16x8;
typedef __attribute__((ext_vector_type(4))) short s16x4;
typedef __attribute__((ext_vector_type(4))) unsigned short u16x4;

__device__ __forceinline__ unsigned short f2bf(float f) {
  unsigned int u = __float_as_uint(f);
  u += 0x7fffu + ((u >> 16) & 1u);  // RNE
  return (unsigned short)(u >> 16);
}
__device__ __forceinline__ float b2f(unsigned short s) {
  return __uint_as_float(((unsigned int)s) << 16);
}

__device__ __forceinline__ f32x4 mfma16x16x16_bf16(s16x4 a, s16x4 b, f32x4 c) {
#if __has_builtin(__builtin_amdgcn_mfma_f32_16x16x16bf16_1k)
  return __builtin_amdgcn_mfma_f32_16x16x16bf16_1k(a, b, c, 0, 0, 0);
#else
  f32x4 d;
  asm volatile("v_mfma_f32_16x16x16_bf16 %0, %1, %2, %3"
               : "=v"(d)
               : "v"(a), "v"(b), "v"(c));
  return d;
#endif
}

// ---------------------------------------------------------------------------
// fp32 -> bf16 elementwise (x)
// ---------------------------------------------------------------------------
__global__ __launch_bounds__(256) void conv_x(const float* __restrict__ x,
                                              unsigned short* __restrict__ xb, int n4) {
  int i = blockIdx.x * 256 + threadIdx.x;
  if (i < n4) {
    f32x4 v = *(const f32x4*)(x + (size_t)i * 4);
    u16x4 o;
#pragma unroll
    for (int j = 0; j < 4; ++j) o[j] = f2bf(v[j]);
    *(u16x4*)(xb + (size_t)i * 4) = o;
  }
}

// ---------------------------------------------------------------------------
// W[K][N] fp32 -> Wt[N][K] bf16 (LDS tile transpose)
// ---------------------------------------------------------------------------
__global__ __launch_bounds__(256) void trans_w(const float* __restrict__ W,
                                               unsigned short* __restrict__ Wt,
                                               int K, int N) {
  __shared__ float T[64][65];
  const int k0 = blockIdx.y * 64, n0 = blockIdx.x * 64;
  const int tid = threadIdx.x;
#pragma unroll
  for (int i = 0; i < 16; ++i) {
    int e = tid + i * 256;
    int r = e >> 6, c = e & 63;
    T[r][c] = W[(size_t)(k0 + r) * N + n0 + c];
  }
  __syncthreads();
#pragma unroll
  for (int i = 0; i < 16; ++i) {
    int e = tid + i * 256;
    int r = e >> 6, c = e & 63;
    Wt[(size_t)(n0 + r) * K + k0 + c] = f2bf(T[c][r]);
  }
}

// ---------------------------------------------------------------------------
// RoPE cos/sin table [L][32]
// ---------------------------------------------------------------------------
__global__ __launch_bounds__(256) void rope_tab(f32x2* __restrict__ tab) {
  int i = blockIdx.x * 256 + threadIdx.x;  // L_*32
  int l = i >> 5, j = i & 31;
  float inv = expf(-(float)j * (9.210340371976184f / 32.0f));  // 10000^(-j/32)
  float ang = (float)l * inv;
  f32x2 cs;
  cs[0] = cosf(ang);
  cs[1] = sinf(ang);
  tab[i] = cs;
}

// ---------------------------------------------------------------------------
// bf16 MFMA GEMM (unchanged from round 3): C = [silu](A @ Bt^T).
// ---------------------------------------------------------------------------
template <int MODE>
__global__ __launch_bounds__(256) void gemm_bf16(const unsigned short* __restrict__ A,
                                                 const unsigned short* __restrict__ Bt,
                                                 void* __restrict__ Cp,
                                                 int M, int N, int K) {
  alignas(16) __shared__ unsigned short As[128][40];
  alignas(16) __shared__ unsigned short Bs[128][40];
  const int tid = threadIdx.x;
  const int lane = tid & 63, w = tid >> 6;
  const int quad = lane >> 4, l15 = lane & 15;
  const int wr = w >> 1, wc = w & 1;
  const int m0 = blockIdx.y * 128, n0 = blockIdx.x * 128;
  f32x4 acc[4][4] = {};
  for (int k0 = 0; k0 < K; k0 += 32) {
#pragma unroll
    for (int i = 0; i < 2; ++i) {
      int ch = tid + i * 256;
      int r = ch >> 2, c = ch & 3;  // 128 rows x 4 chunks (32 cols)
      *(s16x8*)&As[r][c * 8] = *(const s16x8*)(A + (size_t)(m0 + r) * K + k0 + c * 8);
      *(s16x8*)&Bs[r][c * 8] = *(const s16x8*)(Bt + (size_t)(n0 + r) * K + k0 + c * 8);
    }
    __syncthreads();
    s16x8 af[4], bf[4];
#pragma unroll
    for (int mi = 0; mi < 4; ++mi) af[mi] = *(const s16x8*)&As[wr * 64 + mi * 16 + l15][quad * 8];
#pragma unroll
    for (int nj = 0; nj < 4; ++nj) bf[nj] = *(const s16x8*)&Bs[wc * 64 + nj * 16 + l15][quad * 8];
#pragma unroll
    for (int mi = 0; mi < 4; ++mi)
#pragma unroll
      for (int nj = 0; nj < 4; ++nj)
        acc[mi][nj] = __builtin_amdgcn_mfma_f32_16x16x32_bf16(af[mi], bf[nj], acc[mi][nj], 0, 0, 0);
    __syncthreads();
  }
#pragma unroll
  for (int mi = 0; mi < 4; ++mi)
#pragma unroll
    for (int nj = 0; nj < 4; ++nj)
#pragma unroll
      for (int reg = 0; reg < 4; ++reg) {
        int rg = m0 + wr * 64 + mi * 16 + quad * 4 + reg;
        int cg = n0 + wc * 64 + nj * 16 + l15;
        float v = acc[mi][nj][reg];
        if (MODE == 1) {
          v = v / (1.0f + __expf(-v));  // silu
          ((unsigned short*)Cp)[(size_t)rg * N + cg] = f2bf(v);
        } else {
          ((float*)Cp)[(size_t)rg * N + cg] = v;
        }
      }
}

// ---------------------------------------------------------------------------
// In-place RoPE on q,k quarters of qkuv_bf + build v_t[bh][64 d][L] bf16.
// ---------------------------------------------------------------------------
__global__ __launch_bounds__(256) void rope_conv(unsigned short* __restrict__ qk,
                                                 unsigned short* __restrict__ vt,
                                                 const f32x2* __restrict__ tab) {
  alignas(16) __shared__ unsigned short Vsh[64][72];
  const int tid = threadIdx.x;
  const int bh = blockIdx.y, b = bh >> 4, h = bh & 15;
  const int l0 = blockIdx.x * 64;
#pragma unroll
  for (int i = 0; i < 2; ++i) {
    int p = tid + i * 256;
    int row = p >> 3, c4 = p & 7;
    int l = l0 + row;
    size_t base = (size_t)(b * L_ + l) * 4096 + h * 64 + c4 * 4;
#pragma unroll
    for (int t = 0; t < 2; ++t) {  // 0: q, 1: k
      size_t o = base + (size_t)t * 1024;
      u16x4 lo = *(u16x4*)(qk + o);
      u16x4 hi = *(u16x4*)(qk + o + 32);
      u16x4 nlo, nhi;
#pragma unroll
      for (int jj = 0; jj < 4; ++jj) {
        f32x2 cs = tab[l * 32 + c4 * 4 + jj];
        float fl = b2f(lo[jj]), fh = b2f(hi[jj]);
        nlo[jj] = f2bf(fl * cs[0] - fh * cs[1]);
        nhi[jj] = f2bf(fh * cs[0] + fl * cs[1]);
      }
      *(u16x4*)(qk + o) = nlo;
      *(u16x4*)(qk + o + 32) = nhi;
    }
  }
#pragma unroll
  for (int i = 0; i < 2; ++i) {
    int ch = tid + i * 256;
    int row = ch >> 3, c8 = ch & 7;
    *(s16x8*)&Vsh[row][c8 * 8] =
        *(const s16x8*)(qk + (size_t)(b * L_ + l0 + row) * 4096 + 2048 + h * 64 + c8 * 8);
  }
  __syncthreads();
#pragma unroll
  for (int i = 0; i < 2; ++i) {
    int ch = tid + i * 256;
    int drow = ch >> 3, c8 = ch & 7;
    s16x8 o;
#pragma unroll
    for (int jj = 0; jj < 8; ++jj) o[jj] = (short)Vsh[c8 * 8 + jj][drow];
    *(s16x8*)(vt + (size_t)(bh * 64 + drow) * 2048 + l0 + c8 * 8) = o;
  }
}

// ---------------------------------------------------------------------------
// Fused MFMA attention v2: no P LDS round-trip.
// Block = one (b,h) x 128 q-rows; wave w owns 32 q-rows (2 subtiles of 16).
// Per 64-key tile:
//   S^T chunk = mfma_16x16x32(a=K[key][d], b=Q[q][d])  -> C: (key=quad*4+reg,
//   q=l15). Epilogue (scale+cmask*cb, silu, *amask) in registers; the C-layout
//   reinterpreted per-lane IS the A-operand of mfma_16x16x16 (m=q=l15,
//   k=key=quad*4+j) -> feed P directly into PV, B-operand = V^T frags (b64).
// Q b-frags hoisted to registers for the whole block (global, once).
// LN over d=64 via shfl-xor within 16-lane groups; u-gate; bf16 out.
// ---------------------------------------------------------------------------
__global__ __launch_bounds__(256) void attn_mfma(
    const unsigned short* __restrict__ qk, const unsigned short* __restrict__ vt,
    const float* __restrict__ amask, const float* __restrict__ cmask,
    const float* __restrict__ cbias, const float* __restrict__ gamma,
    const float* __restrict__ beta, unsigned short* __restrict__ attng) {
  alignas(16) __shared__ unsigned short Ks[64][72];   // [key][d]
  alignas(16) __shared__ unsigned short Vts[64][72];  // [d][key]
  const int tid = threadIdx.x;
  const int lane = tid & 63, w = tid >> 6;
  const int quad = lane >> 4, l15 = lane & 15;
  const int bh = blockIdx.y, b = bh >> 4, h = bh & 15;
  const int l0 = blockIdx.x * 128;
  const float cb = cbias[h];

  // Hoist Q fragments for this wave's 32 q-rows (b-operand of S^T mfma):
  // qf[qs][s]: lane l15 = q within subtile, k = s*32 + quad*8 + j.
  s16x8 qf[2][2];
#pragma unroll
  for (int qs = 0; qs < 2; ++qs) {
    int qg = l0 + w * 32 + qs * 16 + l15;
#pragma unroll
    for (int s = 0; s < 2; ++s)
      qf[qs][s] = *(const s16x8*)(qk + (size_t)(b * L_ + qg) * 4096 + h * 64 + s * 32 + quad * 8);
  }

  f32x4 oacc[2][4] = {};  // [qs][dt] C-layout: row=q=quad*4+reg, col=d=dt*16+l15

  for (int m0 = 0; m0 < L_; m0 += 64) {
    __syncthreads();  // prev-iter LDS reads complete
#pragma unroll
    for (int i = 0; i < 2; ++i) {  // stage K,V tiles: 64 rows x 8 chunks each
      int ch = tid + i * 256;
      int r = ch >> 3, c = ch & 7;
      *(s16x8*)&Ks[r][c * 8] =
          *(const s16x8*)(qk + (size_t)(b * L_ + m0 + r) * 4096 + 1024 + h * 64 + c * 8);
      *(s16x8*)&Vts[r][c * 8] = *(const s16x8*)(vt + (size_t)(bh * 64 + r) * 2048 + m0 + c * 8);
    }
    // Prefetch masks (vectorized along key): cm4[kt][r], am4[qs][kt][r]
    f32x4 cm4[4], am4[2][4];
#pragma unroll
    for (int kt = 0; kt < 4; ++kt)
      cm4[kt] = *(const f32x4*)(cmask + (size_t)b * L_ + m0 + kt * 16 + quad * 4);
#pragma unroll
    for (int qs = 0; qs < 2; ++qs) {
      int qg = l0 + w * 32 + qs * 16 + l15;
#pragma unroll
      for (int kt = 0; kt < 4; ++kt)
        am4[qs][kt] =
            *(const f32x4*)(amask + ((size_t)b * L_ + qg) * L_ + m0 + kt * 16 + quad * 4);
    }
    __syncthreads();  // staged K/V visible

    // S^T = K @ Q^T over d=64 (two K=32 steps)
    f32x4 sacc[2][4] = {};  // [qs][kt]
#pragma unroll
    for (int s = 0; s < 2; ++s) {
      s16x8 kf[4];
#pragma unroll
      for (int kt = 0; kt < 4; ++kt)
        kf[kt] = *(const s16x8*)&Ks[kt * 16 + l15][s * 32 + quad * 8];
#pragma unroll
      for (int qs = 0; qs < 2; ++qs)
#pragma unroll
        for (int kt = 0; kt < 4; ++kt)
          sacc[qs][kt] = __builtin_amdgcn_mfma_f32_16x16x32_bf16(kf[kt], qf[qs][s],
                                                                 sacc[qs][kt], 0, 0, 0);
    }

    // Epilogue in registers -> P fragments (A-operand of 16x16x16)
    s16x4 pf[2][4];
#pragma unroll
    for (int qs = 0; qs < 2; ++qs)
#pragma unroll
      for (int kt = 0; kt < 4; ++kt) {
#pragma unroll
        for (int r = 0; r < 4; ++r) {
          float v = sacc[qs][kt][r] * 0.125f + cm4[kt][r] * cb;
          v = v / (1.0f + __expf(-v));
          v *= am4[qs][kt][r];
          pf[qs][kt][r] = (short)f2bf(v);
        }
      }

    // O += P @ V (K=16 per kt chunk), B-operand from V^T tile in LDS (b64)
#pragma unroll
    for (int dt = 0; dt < 4; ++dt)
#pragma unroll
      for (int kt = 0; kt < 4; ++kt) {
        s16x4 vf = *(const s16x4*)&Vts[dt * 16 + l15][kt * 16 + quad * 4];
#pragma unroll
        for (int qs = 0; qs < 2; ++qs)
          oacc[qs][dt] = mfma16x16x16_bf16(pf[qs][kt], vf, oacc[qs][dt]);
      }
  }

  // LayerNorm over d=64 + u-gate + store
  const float ga = gamma[0 * 16 + l15];  // per-dt loaded below
#pragma unroll
  for (int qs = 0; qs < 2; ++qs) {
    float sm[4], sq[4];
#pragma unroll
    for (int reg = 0; reg < 4; ++reg) {
      float s1 = 0.f, s2 = 0.f;
#pragma unroll
      for (int dt = 0; dt < 4; ++dt) {
        float v = oacc[qs][dt][reg];
        s1 += v;
        s2 += v * v;
      }
      sm[reg] = s1;
      sq[reg] = s2;
    }
#pragma unroll
    for (int m = 1; m < 16; m <<= 1) {
#pragma unroll
      for (int reg = 0; reg < 4; ++reg) {
        sm[reg] += __shfl_xor(sm[reg], m);
        sq[reg] += __shfl_xor(sq[reg], m);
      }
    }
    float mu[4], rs[4];
#pragma unroll
    for (int reg = 0; reg < 4; ++reg) {
      mu[reg] = sm[reg] * (1.0f / 64.0f);
      float var = sq[reg] * (1.0f / 64.0f) - mu[reg] * mu[reg];
      rs[reg] = rsqrtf(var + 1e-5f);
    }
#pragma unroll
    for (int dt = 0; dt < 4; ++dt) {
      float g = gamma[dt * 16 + l15], be = beta[dt * 16 + l15];
#pragma unroll
      for (int reg = 0; reg < 4; ++reg) {
        int rowg = l0 + w * 32 + qs * 16 + quad * 4 + reg;
        int colg = dt * 16 + l15;
        float v = (oacc[qs][dt][reg] - mu[reg]) * rs[reg] * g + be;
        float u = b2f(qk[(size_t)(b * L_ + rowg) * 4096 + 3072 + h * 64 + colg]);
        attng[(size_t)(b * L_ + rowg) * 1024 + h * 64 + colg] = f2bf(v * u);
      }
    }
  }
  (void)ga;
}

extern "C" void kernel_launch(void* const* d_in, const int* in_sizes, int n_in,
                              void* d_out, int out_size, void* d_ws, size_t ws_size,
                              hipStream_t stream) {
  const float* x = (const float*)d_in[0];
  const float* amask = (const float*)d_in[1];
  const float* cmask = (const float*)d_in[2];
  const float* Wqkuv = (const float*)d_in[3];
  const float* Wout = (const float*)d_in[4];
  const float* gamma = (const float*)d_in[5];
  const float* beta = (const float*)d_in[6];
  const float* cbias = (const float*)d_in[7];
  float* out = (float*)d_out;

  char* ws = (char*)d_ws;
  unsigned short* qkuv_bf = (unsigned short*)ws;                    // 64 MB
  unsigned short* vt = (unsigned short*)(ws + ((size_t)64 << 20));  // 16 MB
  unsigned short* xbf = (unsigned short*)(ws + ((size_t)80 << 20));  // 16 MB
  unsigned short* Wt = (unsigned short*)(ws + ((size_t)96 << 20));   // 8 MB
  unsigned short* Wot = (unsigned short*)(ws + ((size_t)104 << 20)); // 2 MB
  unsigned short* attng = (unsigned short*)(ws + ((size_t)106 << 20)); // 16 MB
  f32x2* tab = (f32x2*)(ws + ((size_t)122 << 20));                   // 0.5 MB

  conv_x<<<8192, 256, 0, stream>>>(x, xbf, (B_ * L_ * D_) / 4);
  trans_w<<<dim3(4096 / 64, 1024 / 64), 256, 0, stream>>>(Wqkuv, Wt, 1024, 4096);
  trans_w<<<dim3(1024 / 64, 1024 / 64), 256, 0, stream>>>(Wout, Wot, 1024, 1024);
  rope_tab<<<(L_ * 32) / 256, 256, 0, stream>>>(tab);

  gemm_bf16<1><<<dim3(4096 / 128, 8192 / 128), 256, 0, stream>>>(xbf, Wt, qkuv_bf,
                                                                 B_ * L_, 4 * D_, D_);
  rope_conv<<<dim3(L_ / 64, B_ * H_), 256, 0, stream>>>(qkuv_bf, vt, tab);
  attn_mfma<<<dim3(L_ / 128, B_ * H_), 256, 0, stream>>>(qkuv_bf, vt, amask, cmask, cbias,
                                                         gamma, beta, attng);
  gemm_bf16<0><<<dim3(1024 / 128, 8192 / 128), 256, 0, stream>>>(attng, Wot, out,
                                                                 B_ * L_, D_, D_);
}

// Round 5
// 468.805 us; speedup vs baseline: 6.6758x; 1.1295x over previous
//
#include <hip/hip_runtime.h>
#include <math.h>
#include <stdint.h>

#define B_ 4
#define L_ 2048
#define D_ 1024
#define H_ 16

typedef __attribute__((ext_vector_type(4))) float f32x4;
typedef __attribute__((ext_vector_type(2))) float f32x2;
typedef __attribute__((ext_vector_type(8))) short s16x8;
typedef __attribute__((ext_vector_type(4))) short s16x4;
typedef __attribute__((ext_vector_type(4))) unsigned short u16x4;

__device__ __forceinline__ unsigned short f2bf(float f) {
  unsigned int u = __float_as_uint(f);
  u += 0x7fffu + ((u >> 16) & 1u);  // RNE
  return (unsigned short)(u >> 16);
}
__device__ __forceinline__ float b2f(unsigned short s) {
  return __uint_as_float(((unsigned int)s) << 16);
}
// silu via fast rcp (1-ulp) — avoids the ~9-inst IEEE fp32 divide sequence
__device__ __forceinline__ float silu_fast(float v) {
  return v * __builtin_amdgcn_rcpf(1.0f + __expf(-v));
}
// async global->LDS DMA, 16B per lane; lds dest = wave-uniform base + lane*16
__device__ __forceinline__ void gl_lds16(const void* g, void* l) {
  __builtin_amdgcn_global_load_lds(
      (__attribute__((address_space(1))) void*)(uintptr_t)g,
      (__attribute__((address_space(3))) void*)(uint32_t)(uintptr_t)l, 16, 0, 0);
}

__device__ __forceinline__ f32x4 mfma16x16x16_bf16(s16x4 a, s16x4 b, f32x4 c) {
#if __has_builtin(__builtin_amdgcn_mfma_f32_16x16x16bf16_1k)
  return __builtin_amdgcn_mfma_f32_16x16x16bf16_1k(a, b, c, 0, 0, 0);
#else
  f32x4 d;
  asm volatile("v_mfma_f32_16x16x16_bf16 %0, %1, %2, %3"
               : "=v"(d)
               : "v"(a), "v"(b), "v"(c));
  return d;
#endif
}

// ---------------------------------------------------------------------------
// fp32 -> bf16 elementwise (x)
// ---------------------------------------------------------------------------
__global__ __launch_bounds__(256) void conv_x(const float* __restrict__ x,
                                              unsigned short* __restrict__ xb, int n4) {
  int i = blockIdx.x * 256 + threadIdx.x;
  if (i < n4) {
    f32x4 v = *(const f32x4*)(x + (size_t)i * 4);
    u16x4 o;
#pragma unroll
    for (int j = 0; j < 4; ++j) o[j] = f2bf(v[j]);
    *(u16x4*)(xb + (size_t)i * 4) = o;
  }
}

// ---------------------------------------------------------------------------
// W[K][N] fp32 -> Wt[N][K] bf16 (LDS tile transpose)
// ---------------------------------------------------------------------------
__global__ __launch_bounds__(256) void trans_w(const float* __restrict__ W,
                                               unsigned short* __restrict__ Wt,
                                               int K, int N) {
  __shared__ float T[64][65];
  const int k0 = blockIdx.y * 64, n0 = blockIdx.x * 64;
  const int tid = threadIdx.x;
#pragma unroll
  for (int i = 0; i < 16; ++i) {
    int e = tid + i * 256;
    int r = e >> 6, c = e & 63;
    T[r][c] = W[(size_t)(k0 + r) * N + n0 + c];
  }
  __syncthreads();
#pragma unroll
  for (int i = 0; i < 16; ++i) {
    int e = tid + i * 256;
    int r = e >> 6, c = e & 63;
    Wt[(size_t)(n0 + r) * K + k0 + c] = f2bf(T[c][r]);
  }
}

// ---------------------------------------------------------------------------
// RoPE cos/sin table [L][32]
// ---------------------------------------------------------------------------
__global__ __launch_bounds__(256) void rope_tab(f32x2* __restrict__ tab) {
  int i = blockIdx.x * 256 + threadIdx.x;  // L_*32
  int l = i >> 5, j = i & 31;
  float inv = expf(-(float)j * (9.210340371976184f / 32.0f));  // 10000^(-j/32)
  float ang = (float)l * inv;
  f32x2 cs;
  cs[0] = cosf(ang);
  cs[1] = sinf(ang);
  tab[i] = cs;
}

// ---------------------------------------------------------------------------
// bf16 MFMA GEMM v2 (m97 structure): C = [silu](A @ Bt^T).
// 128x128 tile, BK=32, 256 threads = 4 waves (2x2 of 64x64).
// Staging via global_load_lds width=16 into UNPADDED [128][32] tiles with an
// XOR chunk swizzle: LDS[r][chunk c] holds global chunk c ^ ((r>>1)&3).
// Frag reads then hit all 32 banks exactly 2-way (free, m136).
// ---------------------------------------------------------------------------
template <int MODE>
__global__ __launch_bounds__(256) void gemm_bf16(const unsigned short* __restrict__ A,
                                                 const unsigned short* __restrict__ Bt,
                                                 void* __restrict__ Cp,
                                                 int M, int N, int K) {
  alignas(16) __shared__ unsigned short As[128][32];
  alignas(16) __shared__ unsigned short Bs[128][32];
  const int tid = threadIdx.x;
  const int lane = tid & 63, w = tid >> 6;
  const int quad = lane >> 4, l15 = lane & 15;
  const int wr = w >> 1, wc = w & 1;
  const int m0 = blockIdx.y * 128, n0 = blockIdx.x * 128;
  // staging: lane -> dest row r0+(lane>>2), dest chunk lane&3;
  // source chunk = (lane&3) ^ ((lane>>3)&3)  (== dest chunk ^ ((row>>1)&3))
  const int srow = lane >> 2;
  const int schunk = (lane & 3) ^ ((lane >> 3) & 3);
  // frag reads: logical chunk quad lives at column (quad ^ ((l15>>1)&3))*8
  const int fcol = (quad ^ ((l15 >> 1) & 3)) * 8;
  f32x4 acc[4][4] = {};
  for (int k0 = 0; k0 < K; k0 += 32) {
    __syncthreads();  // prev-iter frag reads complete before overwrite
#pragma unroll
    for (int i = 0; i < 2; ++i) {
      int r0 = (w * 2 + i) * 16;
      gl_lds16(A + (size_t)(m0 + r0 + srow) * K + k0 + schunk * 8, &As[r0][0]);
      gl_lds16(Bt + (size_t)(n0 + r0 + srow) * K + k0 + schunk * 8, &Bs[r0][0]);
    }
    __syncthreads();  // compiler drains vmcnt(0) before barrier -> DMA done
    s16x8 af[4], bf[4];
#pragma unroll
    for (int mi = 0; mi < 4; ++mi) af[mi] = *(const s16x8*)&As[wr * 64 + mi * 16 + l15][fcol];
#pragma unroll
    for (int nj = 0; nj < 4; ++nj) bf[nj] = *(const s16x8*)&Bs[wc * 64 + nj * 16 + l15][fcol];
#pragma unroll
    for (int mi = 0; mi < 4; ++mi)
#pragma unroll
      for (int nj = 0; nj < 4; ++nj)
        acc[mi][nj] = __builtin_amdgcn_mfma_f32_16x16x32_bf16(af[mi], bf[nj], acc[mi][nj], 0, 0, 0);
  }
#pragma unroll
  for (int mi = 0; mi < 4; ++mi)
#pragma unroll
    for (int nj = 0; nj < 4; ++nj)
#pragma unroll
      for (int reg = 0; reg < 4; ++reg) {
        int rg = m0 + wr * 64 + mi * 16 + quad * 4 + reg;
        int cg = n0 + wc * 64 + nj * 16 + l15;
        float v = acc[mi][nj][reg];
        if (MODE == 1) {
          ((unsigned short*)Cp)[(size_t)rg * N + cg] = f2bf(silu_fast(v));
        } else {
          ((float*)Cp)[(size_t)rg * N + cg] = v;
        }
      }
}

// ---------------------------------------------------------------------------
// In-place RoPE on q,k quarters of qkuv_bf + build v_t[bh][64 d][L] bf16.
// ---------------------------------------------------------------------------
__global__ __launch_bounds__(256) void rope_conv(unsigned short* __restrict__ qk,
                                                 unsigned short* __restrict__ vt,
                                                 const f32x2* __restrict__ tab) {
  alignas(16) __shared__ unsigned short Vsh[64][72];
  const int tid = threadIdx.x;
  const int bh = blockIdx.y, b = bh >> 4, h = bh & 15;
  const int l0 = blockIdx.x * 64;
#pragma unroll
  for (int i = 0; i < 2; ++i) {
    int p = tid + i * 256;
    int row = p >> 3, c4 = p & 7;
    int l = l0 + row;
    size_t base = (size_t)(b * L_ + l) * 4096 + h * 64 + c4 * 4;
#pragma unroll
    for (int t = 0; t < 2; ++t) {  // 0: q, 1: k
      size_t o = base + (size_t)t * 1024;
      u16x4 lo = *(u16x4*)(qk + o);
      u16x4 hi = *(u16x4*)(qk + o + 32);
      u16x4 nlo, nhi;
#pragma unroll
      for (int jj = 0; jj < 4; ++jj) {
        f32x2 cs = tab[l * 32 + c4 * 4 + jj];
        float fl = b2f(lo[jj]), fh = b2f(hi[jj]);
        nlo[jj] = f2bf(fl * cs[0] - fh * cs[1]);
        nhi[jj] = f2bf(fh * cs[0] + fl * cs[1]);
      }
      *(u16x4*)(qk + o) = nlo;
      *(u16x4*)(qk + o + 32) = nhi;
    }
  }
#pragma unroll
  for (int i = 0; i < 2; ++i) {
    int ch = tid + i * 256;
    int row = ch >> 3, c8 = ch & 7;
    *(s16x8*)&Vsh[row][c8 * 8] =
        *(const s16x8*)(qk + (size_t)(b * L_ + l0 + row) * 4096 + 2048 + h * 64 + c8 * 8);
  }
  __syncthreads();
#pragma unroll
  for (int i = 0; i < 2; ++i) {
    int ch = tid + i * 256;
    int drow = ch >> 3, c8 = ch & 7;
    s16x8 o;
#pragma unroll
    for (int jj = 0; jj < 8; ++jj) o[jj] = (short)Vsh[c8 * 8 + jj][drow];
    *(s16x8*)(vt + (size_t)(bh * 64 + drow) * 2048 + l0 + c8 * 8) = o;
  }
}

// ---------------------------------------------------------------------------
// Fused MFMA attention v3 (v2 + cheap epilogue).
// Block = one (b,h) x 128 q-rows; wave w owns 32 q-rows (2 subtiles of 16).
// S^T via mfma(a=K,b=Q) -> in-register scale/bias/silu/mask (rcp-silu,
// hoisted cmask*cb) -> P is directly the A-operand of mfma_16x16x16 -> PV.
// LN over d=64 via shfl-xor; u-gate; bf16 out.
// ---------------------------------------------------------------------------
__global__ __launch_bounds__(256) void attn_mfma(
    const unsigned short* __restrict__ qk, const unsigned short* __restrict__ vt,
    const float* __restrict__ amask, const float* __restrict__ cmask,
    const float* __restrict__ cbias, const float* __restrict__ gamma,
    const float* __restrict__ beta, unsigned short* __restrict__ attng) {
  alignas(16) __shared__ unsigned short Ks[64][72];   // [key][d]
  alignas(16) __shared__ unsigned short Vts[64][72];  // [d][key]
  const int tid = threadIdx.x;
  const int lane = tid & 63, w = tid >> 6;
  const int quad = lane >> 4, l15 = lane & 15;
  const int bh = blockIdx.y, b = bh >> 4, h = bh & 15;
  const int l0 = blockIdx.x * 128;
  const float cb = cbias[h];

  // Hoist Q fragments for this wave's 32 q-rows (b-operand of S^T mfma)
  s16x8 qf[2][2];
#pragma unroll
  for (int qs = 0; qs < 2; ++qs) {
    int qg = l0 + w * 32 + qs * 16 + l15;
#pragma unroll
    for (int s = 0; s < 2; ++s)
      qf[qs][s] = *(const s16x8*)(qk + (size_t)(b * L_ + qg) * 4096 + h * 64 + s * 32 + quad * 8);
  }

  f32x4 oacc[2][4] = {};  // [qs][dt] C-layout: row=q=quad*4+reg, col=d=dt*16+l15

  for (int m0 = 0; m0 < L_; m0 += 64) {
    __syncthreads();  // prev-iter LDS reads complete
#pragma unroll
    for (int i = 0; i < 2; ++i) {  // stage K,V tiles: 64 rows x 8 chunks each
      int ch = tid + i * 256;
      int r = ch >> 3, c = ch & 7;
      *(s16x8*)&Ks[r][c * 8] =
          *(const s16x8*)(qk + (size_t)(b * L_ + m0 + r) * 4096 + 1024 + h * 64 + c * 8);
      *(s16x8*)&Vts[r][c * 8] = *(const s16x8*)(vt + (size_t)(bh * 64 + r) * 2048 + m0 + c * 8);
    }
    // Prefetch masks (vectorized along key); hoist cm*cb
    f32x4 cmcb[4], am4[2][4];
#pragma unroll
    for (int kt = 0; kt < 4; ++kt) {
      f32x4 cm = *(const f32x4*)(cmask + (size_t)b * L_ + m0 + kt * 16 + quad * 4);
      cmcb[kt] = cm * cb;
    }
#pragma unroll
    for (int qs = 0; qs < 2; ++qs) {
      int qg = l0 + w * 32 + qs * 16 + l15;
#pragma unroll
      for (int kt = 0; kt < 4; ++kt)
        am4[qs][kt] =
            *(const f32x4*)(amask + ((size_t)b * L_ + qg) * L_ + m0 + kt * 16 + quad * 4);
    }
    __syncthreads();  // staged K/V visible

    // S^T = K @ Q^T over d=64 (two K=32 steps)
    f32x4 sacc[2][4] = {};  // [qs][kt]
#pragma unroll
    for (int s = 0; s < 2; ++s) {
      s16x8 kf[4];
#pragma unroll
      for (int kt = 0; kt < 4; ++kt)
        kf[kt] = *(const s16x8*)&Ks[kt * 16 + l15][s * 32 + quad * 8];
#pragma unroll
      for (int qs = 0; qs < 2; ++qs)
#pragma unroll
        for (int kt = 0; kt < 4; ++kt)
          sacc[qs][kt] = __builtin_amdgcn_mfma_f32_16x16x32_bf16(kf[kt], qf[qs][s],
                                                                 sacc[qs][kt], 0, 0, 0);
    }

    // Epilogue in registers -> P fragments (A-operand of 16x16x16)
    s16x4 pf[2][4];
#pragma unroll
    for (int qs = 0; qs < 2; ++qs)
#pragma unroll
      for (int kt = 0; kt < 4; ++kt) {
#pragma unroll
        for (int r = 0; r < 4; ++r) {
          float v = fmaf(sacc[qs][kt][r], 0.125f, cmcb[kt][r]);
          v = silu_fast(v);
          v *= am4[qs][kt][r];
          pf[qs][kt][r] = (short)f2bf(v);
        }
      }

    // O += P @ V (K=16 per kt chunk), B-operand from V^T tile in LDS (b64)
#pragma unroll
    for (int dt = 0; dt < 4; ++dt)
#pragma unroll
      for (int kt = 0; kt < 4; ++kt) {
        s16x4 vf = *(const s16x4*)&Vts[dt * 16 + l15][kt * 16 + quad * 4];
#pragma unroll
        for (int qs = 0; qs < 2; ++qs)
          oacc[qs][dt] = mfma16x16x16_bf16(pf[qs][kt], vf, oacc[qs][dt]);
      }
  }

  // LayerNorm over d=64 + u-gate + store
#pragma unroll
  for (int qs = 0; qs < 2; ++qs) {
    float sm[4], sq[4];
#pragma unroll
    for (int reg = 0; reg < 4; ++reg) {
      float s1 = 0.f, s2 = 0.f;
#pragma unroll
      for (int dt = 0; dt < 4; ++dt) {
        float v = oacc[qs][dt][reg];
        s1 += v;
        s2 += v * v;
      }
      sm[reg] = s1;
      sq[reg] = s2;
    }
#pragma unroll
    for (int m = 1; m < 16; m <<= 1) {
#pragma unroll
      for (int reg = 0; reg < 4; ++reg) {
        sm[reg] += __shfl_xor(sm[reg], m);
        sq[reg] += __shfl_xor(sq[reg], m);
      }
    }
    float mu[4], rs[4];
#pragma unroll
    for (int reg = 0; reg < 4; ++reg) {
      mu[reg] = sm[reg] * (1.0f / 64.0f);
      float var = sq[reg] * (1.0f / 64.0f) - mu[reg] * mu[reg];
      rs[reg] = rsqrtf(var + 1e-5f);
    }
#pragma unroll
    for (int dt = 0; dt < 4; ++dt) {
      float g = gamma[dt * 16 + l15], be = beta[dt * 16 + l15];
#pragma unroll
      for (int reg = 0; reg < 4; ++reg) {
        int rowg = l0 + w * 32 + qs * 16 + quad * 4 + reg;
        int colg = dt * 16 + l15;
        float v = (oacc[qs][dt][reg] - mu[reg]) * rs[reg] * g + be;
        float u = b2f(qk[(size_t)(b * L_ + rowg) * 4096 + 3072 + h * 64 + colg]);
        attng[(size_t)(b * L_ + rowg) * 1024 + h * 64 + colg] = f2bf(v * u);
      }
    }
  }
}

extern "C" void kernel_launch(void* const* d_in, const int* in_sizes, int n_in,
                              void* d_out, int out_size, void* d_ws, size_t ws_size,
                              hipStream_t stream) {
  const float* x = (const float*)d_in[0];
  const float* amask = (const float*)d_in[1];
  const float* cmask = (const float*)d_in[2];
  const float* Wqkuv = (const float*)d_in[3];
  const float* Wout = (const float*)d_in[4];
  const float* gamma = (const float*)d_in[5];
  const float* beta = (const float*)d_in[6];
  const float* cbias = (const float*)d_in[7];
  float* out = (float*)d_out;

  char* ws = (char*)d_ws;
  unsigned short* qkuv_bf = (unsigned short*)ws;                    // 64 MB
  unsigned short* vt = (unsigned short*)(ws + ((size_t)64 << 20));  // 16 MB
  unsigned short* xbf = (unsigned short*)(ws + ((size_t)80 << 20));  // 16 MB
  unsigned short* Wt = (unsigned short*)(ws + ((size_t)96 << 20));   // 8 MB
  unsigned short* Wot = (unsigned short*)(ws + ((size_t)104 << 20)); // 2 MB
  unsigned short* attng = (unsigned short*)(ws + ((size_t)106 << 20)); // 16 MB
  f32x2* tab = (f32x2*)(ws + ((size_t)122 << 20));                   // 0.5 MB

  conv_x<<<8192, 256, 0, stream>>>(x, xbf, (B_ * L_ * D_) / 4);
  trans_w<<<dim3(4096 / 64, 1024 / 64), 256, 0, stream>>>(Wqkuv, Wt, 1024, 4096);
  trans_w<<<dim3(1024 / 64, 1024 / 64), 256, 0, stream>>>(Wout, Wot, 1024, 1024);
  rope_tab<<<(L_ * 32) / 256, 256, 0, stream>>>(tab);

  gemm_bf16<1><<<dim3(4096 / 128, 8192 / 128), 256, 0, stream>>>(xbf, Wt, qkuv_bf,
                                                                 B_ * L_, 4 * D_, D_);
  rope_conv<<<dim3(L_ / 64, B_ * H_), 256, 0, stream>>>(qkuv_bf, vt, tab);
  attn_mfma<<<dim3(L_ / 128, B_ * H_), 256, 0, stream>>>(qkuv_bf, vt, amask, cmask, cbias,
                                                         gamma, beta, attng);
  gemm_bf16<0><<<dim3(1024 / 128, 8192 / 128), 256, 0, stream>>>(attng, Wot, out,
                                                                 B_ * L_, D_, D_);
}

// Round 6
// 461.728 us; speedup vs baseline: 6.7781x; 1.0153x over previous
//
#include <hip/hip_runtime.h>
#include <math.h>
#include <stdint.h>

#define B_ 4
#define L_ 2048
#define D_ 1024
#define H_ 16

typedef __attribute__((ext_vector_type(4))) float f32x4;
typedef __attribute__((ext_vector_type(2))) float f32x2;
typedef __attribute__((ext_vector_type(8))) short s16x8;
typedef __attribute__((ext_vector_type(4))) short s16x4;
typedef __attribute__((ext_vector_type(4))) unsigned short u16x4;
typedef __attribute__((ext_vector_type(4))) unsigned int u32x4;
typedef __attribute__((ext_vector_type(2))) __bf16 bf16x2;

__device__ __forceinline__ unsigned short f2bf(float f) {
  unsigned int u = __float_as_uint(f);
  u += 0x7fffu + ((u >> 16) & 1u);  // RNE
  return (unsigned short)(u >> 16);
}
__device__ __forceinline__ float b2f(unsigned short s) {
  return __uint_as_float(((unsigned int)s) << 16);
}
// packed f32x2 -> bf16x2 (RTNE); lowers to v_cvt_pk_bf16_f32 on gfx950
__device__ __forceinline__ unsigned int pk2(float a, float b) {
  f32x2 v;
  v[0] = a;
  v[1] = b;
  bf16x2 r = __builtin_convertvector(v, bf16x2);
  return __builtin_bit_cast(unsigned int, r);
}
// silu via fast rcp (1-ulp)
__device__ __forceinline__ float silu_fast(float v) {
  return v * __builtin_amdgcn_rcpf(1.0f + __expf(-v));
}
// async global->LDS DMA, 16B per lane; lds dest = wave-uniform base + lane*16
__device__ __forceinline__ void gl_lds16(const void* g, void* l) {
  __builtin_amdgcn_global_load_lds(
      (__attribute__((address_space(1))) void*)(uintptr_t)g,
      (__attribute__((address_space(3))) void*)(uint32_t)(uintptr_t)l, 16, 0, 0);
}

// ---------------------------------------------------------------------------
// fp32 -> bf16 elementwise (x)
// ---------------------------------------------------------------------------
__global__ __launch_bounds__(256) void conv_x(const float* __restrict__ x,
                                              unsigned short* __restrict__ xb, int n4) {
  int i = blockIdx.x * 256 + threadIdx.x;
  if (i < n4) {
    f32x4 v = *(const f32x4*)(x + (size_t)i * 4);
    u16x4 o;
#pragma unroll
    for (int j = 0; j < 4; ++j) o[j] = f2bf(v[j]);
    *(u16x4*)(xb + (size_t)i * 4) = o;
  }
}

// ---------------------------------------------------------------------------
// W[K][N] fp32 -> Wt[N][K] bf16 (LDS tile transpose)
// ---------------------------------------------------------------------------
__global__ __launch_bounds__(256) void trans_w(const float* __restrict__ W,
                                               unsigned short* __restrict__ Wt,
                                               int K, int N) {
  __shared__ float T[64][65];
  const int k0 = blockIdx.y * 64, n0 = blockIdx.x * 64;
  const int tid = threadIdx.x;
#pragma unroll
  for (int i = 0; i < 16; ++i) {
    int e = tid + i * 256;
    int r = e >> 6, c = e & 63;
    T[r][c] = W[(size_t)(k0 + r) * N + n0 + c];
  }
  __syncthreads();
#pragma unroll
  for (int i = 0; i < 16; ++i) {
    int e = tid + i * 256;
    int r = e >> 6, c = e & 63;
    Wt[(size_t)(n0 + r) * K + k0 + c] = f2bf(T[c][r]);
  }
}

// ---------------------------------------------------------------------------
// RoPE cos/sin table [L][32]
// ---------------------------------------------------------------------------
__global__ __launch_bounds__(256) void rope_tab(f32x2* __restrict__ tab) {
  int i = blockIdx.x * 256 + threadIdx.x;  // L_*32
  int l = i >> 5, j = i & 31;
  float inv = expf(-(float)j * (9.210340371976184f / 32.0f));  // 10000^(-j/32)
  float ang = (float)l * inv;
  f32x2 cs;
  cs[0] = cosf(ang);
  cs[1] = sinf(ang);
  tab[i] = cs;
}

// ---------------------------------------------------------------------------
// bf16 MFMA GEMM (unchanged from round 5): C = [silu](A @ Bt^T).
// ---------------------------------------------------------------------------
template <int MODE>
__global__ __launch_bounds__(256) void gemm_bf16(const unsigned short* __restrict__ A,
                                                 const unsigned short* __restrict__ Bt,
                                                 void* __restrict__ Cp,
                                                 int M, int N, int K) {
  alignas(16) __shared__ unsigned short As[128][32];
  alignas(16) __shared__ unsigned short Bs[128][32];
  const int tid = threadIdx.x;
  const int lane = tid & 63, w = tid >> 6;
  const int quad = lane >> 4, l15 = lane & 15;
  const int wr = w >> 1, wc = w & 1;
  const int m0 = blockIdx.y * 128, n0 = blockIdx.x * 128;
  const int srow = lane >> 2;
  const int schunk = (lane & 3) ^ ((lane >> 3) & 3);
  const int fcol = (quad ^ ((l15 >> 1) & 3)) * 8;
  f32x4 acc[4][4] = {};
  for (int k0 = 0; k0 < K; k0 += 32) {
    __syncthreads();
#pragma unroll
    for (int i = 0; i < 2; ++i) {
      int r0 = (w * 2 + i) * 16;
      gl_lds16(A + (size_t)(m0 + r0 + srow) * K + k0 + schunk * 8, &As[r0][0]);
      gl_lds16(Bt + (size_t)(n0 + r0 + srow) * K + k0 + schunk * 8, &Bs[r0][0]);
    }
    __syncthreads();
    s16x8 af[4], bf[4];
#pragma unroll
    for (int mi = 0; mi < 4; ++mi) af[mi] = *(const s16x8*)&As[wr * 64 + mi * 16 + l15][fcol];
#pragma unroll
    for (int nj = 0; nj < 4; ++nj) bf[nj] = *(const s16x8*)&Bs[wc * 64 + nj * 16 + l15][fcol];
#pragma unroll
    for (int mi = 0; mi < 4; ++mi)
#pragma unroll
      for (int nj = 0; nj < 4; ++nj)
        acc[mi][nj] = __builtin_amdgcn_mfma_f32_16x16x32_bf16(af[mi], bf[nj], acc[mi][nj], 0, 0, 0);
  }
#pragma unroll
  for (int mi = 0; mi < 4; ++mi)
#pragma unroll
    for (int nj = 0; nj < 4; ++nj)
#pragma unroll
      for (int reg = 0; reg < 4; ++reg) {
        int rg = m0 + wr * 64 + mi * 16 + quad * 4 + reg;
        int cg = n0 + wc * 64 + nj * 16 + l15;
        float v = acc[mi][nj][reg];
        if (MODE == 1) {
          ((unsigned short*)Cp)[(size_t)rg * N + cg] = f2bf(silu_fast(v));
        } else {
          ((float*)Cp)[(size_t)rg * N + cg] = v;
        }
      }
}

// ---------------------------------------------------------------------------
// In-place RoPE on q,k quarters of qkuv_bf + build v_t[bh][64 d][Lperm] bf16.
// Key axis of vt is PERMUTED within each 32-group so that P fragments (C-layout
// of S^T, pairs of 16-key tiles concatenated) form a valid mfma_16x16x32
// A-operand: position p = 8q+4h+j  <-  local key 16h+4q+j.
// ---------------------------------------------------------------------------
__global__ __launch_bounds__(256) void rope_conv(unsigned short* __restrict__ qk,
                                                 unsigned short* __restrict__ vt,
                                                 const f32x2* __restrict__ tab) {
  alignas(16) __shared__ unsigned short Vsh[64][72];
  const int tid = threadIdx.x;
  const int bh = blockIdx.y, b = bh >> 4, h = bh & 15;
  const int l0 = blockIdx.x * 64;
#pragma unroll
  for (int i = 0; i < 2; ++i) {
    int p = tid + i * 256;
    int row = p >> 3, c4 = p & 7;
    int l = l0 + row;
    size_t base = (size_t)(b * L_ + l) * 4096 + h * 64 + c4 * 4;
#pragma unroll
    for (int t = 0; t < 2; ++t) {  // 0: q, 1: k
      size_t o = base + (size_t)t * 1024;
      u16x4 lo = *(u16x4*)(qk + o);
      u16x4 hi = *(u16x4*)(qk + o + 32);
      u16x4 nlo, nhi;
#pragma unroll
      for (int jj = 0; jj < 4; ++jj) {
        f32x2 cs = tab[l * 32 + c4 * 4 + jj];
        float fl = b2f(lo[jj]), fh = b2f(hi[jj]);
        nlo[jj] = f2bf(fl * cs[0] - fh * cs[1]);
        nhi[jj] = f2bf(fh * cs[0] + fl * cs[1]);
      }
      *(u16x4*)(qk + o) = nlo;
      *(u16x4*)(qk + o + 32) = nhi;
    }
  }
#pragma unroll
  for (int i = 0; i < 2; ++i) {
    int ch = tid + i * 256;
    int row = ch >> 3, c8 = ch & 7;
    *(s16x8*)&Vsh[row][c8 * 8] =
        *(const s16x8*)(qk + (size_t)(b * L_ + l0 + row) * 4096 + 2048 + h * 64 + c8 * 8);
  }
  __syncthreads();
#pragma unroll
  for (int i = 0; i < 2; ++i) {
    int ch = tid + i * 256;
    int drow = ch >> 3, c8 = ch & 7;
    s16x8 o;
#pragma unroll
    for (int jj = 0; jj < 8; ++jj) {
      int pos = c8 * 8 + jj;  // 0..63 within tile
      int g = pos >> 5, p = pos & 31;
      int lk = g * 32 + ((p >> 2) & 1) * 16 + ((p >> 3) & 3) * 4 + (p & 3);
      o[jj] = (short)Vsh[lk][drow];
    }
    *(s16x8*)(vt + (size_t)(bh * 64 + drow) * 2048 + l0 + c8 * 8) = o;
  }
}

// ---------------------------------------------------------------------------
// Fused MFMA attention v4.
// Block = one (b,h) x 128 q-rows; wave w owns 32 q-rows (2 subtiles of 16).
// K/V staged via global_load_lds width=16 into unpadded [64][64] LDS tiles
// with XOR-8 chunk swizzle (physical chunk = logical ^ (row&7)) -> frag reads
// are 2-way bank aliased (free).  S^T via mfma(a=K,b=Q); in-register
// scale/bias/silu/mask epilogue with packed bf16 converts; P pairs feed
// mfma_16x16x32 PV directly (key permutation baked into vt).  LN + u-gate.
// ---------------------------------------------------------------------------
__global__ __launch_bounds__(256) void attn_mfma(
    const unsigned short* __restrict__ qk, const unsigned short* __restrict__ vt,
    const float* __restrict__ amask, const float* __restrict__ cmask,
    const float* __restrict__ cbias, const float* __restrict__ gamma,
    const float* __restrict__ beta, unsigned short* __restrict__ attng) {
  alignas(16) __shared__ unsigned short Ks[64][64];   // [key][d], d-chunks XORed
  alignas(16) __shared__ unsigned short Vts[64][64];  // [d][key], key-chunks XORed
  const int tid = threadIdx.x;
  const int lane = tid & 63, w = tid >> 6;
  const int quad = lane >> 4, l15 = lane & 15;
  const int bh = blockIdx.y, b = bh >> 4, h = bh & 15;
  const int l0 = blockIdx.x * 128;
  const float cb = cbias[h];
  const int srow = lane >> 3;            // 0..7 within a 1KB DMA
  const int schunk = (lane & 7) ^ srow;  // source chunk for XOR-8 store

  // Hoist Q fragments for this wave's 32 q-rows (b-operand of S^T mfma)
  s16x8 qf[2][2];
  const float* abase[2];
#pragma unroll
  for (int qs = 0; qs < 2; ++qs) {
    int qg = l0 + w * 32 + qs * 16 + l15;
#pragma unroll
    for (int s = 0; s < 2; ++s)
      qf[qs][s] = *(const s16x8*)(qk + (size_t)(b * L_ + qg) * 4096 + h * 64 + s * 32 + quad * 8);
    abase[qs] = amask + ((size_t)b * L_ + qg) * L_;
  }
  const float* cbase = cmask + (size_t)b * L_;

  f32x4 oacc[2][4] = {};  // [qs][dt] C-layout: row=q=quad*4+reg, col=d=dt*16+l15

  for (int m0 = 0; m0 < L_; m0 += 64) {
    __syncthreads();  // prev-iter LDS reads complete before DMA overwrite
#pragma unroll
    for (int i = 0; i < 2; ++i) {  // wave w stages rows w*16+i*8 .. +7
      int r0 = w * 16 + i * 8;
      gl_lds16(qk + (size_t)(b * L_ + m0 + r0 + srow) * 4096 + 1024 + h * 64 + schunk * 8,
               &Ks[r0][0]);
      gl_lds16(vt + (size_t)(bh * 64 + r0 + srow) * 2048 + m0 + schunk * 8, &Vts[r0][0]);
    }
    // Masks: one vaddr per qs, 4 imm-offset loads each
    f32x4 cmcb[4], am4[2][4];
#pragma unroll
    for (int kt = 0; kt < 4; ++kt)
      cmcb[kt] = *(const f32x4*)(cbase + m0 + kt * 16 + quad * 4) * cb;
#pragma unroll
    for (int qs = 0; qs < 2; ++qs)
#pragma unroll
      for (int kt = 0; kt < 4; ++kt)
        am4[qs][kt] = *(const f32x4*)(abase[qs] + m0 + kt * 16 + quad * 4);
    __syncthreads();  // vmcnt(0) drain -> DMA + mask loads complete

    // S^T = K @ Q^T over d=64 (two K=32 steps)
    f32x4 sacc[2][4] = {};  // [qs][kt]; C: key=quad*4+reg, q=l15
#pragma unroll
    for (int s = 0; s < 2; ++s) {
      s16x8 kf[4];
#pragma unroll
      for (int kt = 0; kt < 4; ++kt)
        kf[kt] = *(const s16x8*)&Ks[kt * 16 + l15][((s * 4 + quad) ^ (l15 & 7)) * 8];
#pragma unroll
      for (int qs = 0; qs < 2; ++qs)
#pragma unroll
        for (int kt = 0; kt < 4; ++kt)
          sacc[qs][kt] = __builtin_amdgcn_mfma_f32_16x16x32_bf16(kf[kt], qf[qs][s],
                                                                 sacc[qs][kt], 0, 0, 0);
    }

    // Epilogue -> P fragments packed as K=32 A-operands (kt pairs)
    s16x8 pf[2][2];
#pragma unroll
    for (int qs = 0; qs < 2; ++qs)
#pragma unroll
      for (int t = 0; t < 2; ++t) {
        u32x4 pw;
#pragma unroll
        for (int half = 0; half < 2; ++half) {
          int kt = 2 * t + half;
          float x[4];
#pragma unroll
          for (int r = 0; r < 4; ++r) {
            float v = fmaf(sacc[qs][kt][r], 0.125f, cmcb[kt][r]);
            v = silu_fast(v);
            x[r] = v * am4[qs][kt][r];
          }
          pw[half * 2 + 0] = pk2(x[0], x[1]);
          pw[half * 2 + 1] = pk2(x[2], x[3]);
        }
        pf[qs][t] = __builtin_bit_cast(s16x8, pw);
      }

    // O += P @ V, K=32 per group (vt key-permuted to match P's lane layout)
#pragma unroll
    for (int dt = 0; dt < 4; ++dt)
#pragma unroll
      for (int t = 0; t < 2; ++t) {
        s16x8 vf = *(const s16x8*)&Vts[dt * 16 + l15][((t * 4 + quad) ^ (l15 & 7)) * 8];
#pragma unroll
        for (int qs = 0; qs < 2; ++qs)
          oacc[qs][dt] = __builtin_amdgcn_mfma_f32_16x16x32_bf16(pf[qs][t], vf,
                                                                 oacc[qs][dt], 0, 0, 0);
      }
  }

  // LayerNorm over d=64 + u-gate + store
#pragma unroll
  for (int qs = 0; qs < 2; ++qs) {
    float sm[4], sq[4];
#pragma unroll
    for (int reg = 0; reg < 4; ++reg) {
      float s1 = 0.f, s2 = 0.f;
#pragma unroll
      for (int dt = 0; dt < 4; ++dt) {
        float v = oacc[qs][dt][reg];
        s1 += v;
        s2 += v * v;
      }
      sm[reg] = s1;
      sq[reg] = s2;
    }
#pragma unroll
    for (int m = 1; m < 16; m <<= 1) {
#pragma unroll
      for (int reg = 0; reg < 4; ++reg) {
        sm[reg] += __shfl_xor(sm[reg], m);
        sq[reg] += __shfl_xor(sq[reg], m);
      }
    }
    float mu[4], rs[4];
#pragma unroll
    for (int reg = 0; reg < 4; ++reg) {
      mu[reg] = sm[reg] * (1.0f / 64.0f);
      float var = sq[reg] * (1.0f / 64.0f) - mu[reg] * mu[reg];
      rs[reg] = rsqrtf(var + 1e-5f);
    }
#pragma unroll
    for (int dt = 0; dt < 4; ++dt) {
      float g = gamma[dt * 16 + l15], be = beta[dt * 16 + l15];
#pragma unroll
      for (int reg = 0; reg < 4; ++reg) {
        int rowg = l0 + w * 32 + qs * 16 + quad * 4 + reg;
        int colg = dt * 16 + l15;
        float v = (oacc[qs][dt][reg] - mu[reg]) * rs[reg] * g + be;
        float u = b2f(qk[(size_t)(b * L_ + rowg) * 4096 + 3072 + h * 64 + colg]);
        attng[(size_t)(b * L_ + rowg) * 1024 + h * 64 + colg] = f2bf(v * u);
      }
    }
  }
}

extern "C" void kernel_launch(void* const* d_in, const int* in_sizes, int n_in,
                              void* d_out, int out_size, void* d_ws, size_t ws_size,
                              hipStream_t stream) {
  const float* x = (const float*)d_in[0];
  const float* amask = (const float*)d_in[1];
  const float* cmask = (const float*)d_in[2];
  const float* Wqkuv = (const float*)d_in[3];
  const float* Wout = (const float*)d_in[4];
  const float* gamma = (const float*)d_in[5];
  const float* beta = (const float*)d_in[6];
  const float* cbias = (const float*)d_in[7];
  float* out = (float*)d_out;

  char* ws = (char*)d_ws;
  unsigned short* qkuv_bf = (unsigned short*)ws;                    // 64 MB
  unsigned short* vt = (unsigned short*)(ws + ((size_t)64 << 20));  // 16 MB
  unsigned short* xbf = (unsigned short*)(ws + ((size_t)80 << 20));  // 16 MB
  unsigned short* Wt = (unsigned short*)(ws + ((size_t)96 << 20));   // 8 MB
  unsigned short* Wot = (unsigned short*)(ws + ((size_t)104 << 20)); // 2 MB
  unsigned short* attng = (unsigned short*)(ws + ((size_t)106 << 20)); // 16 MB
  f32x2* tab = (f32x2*)(ws + ((size_t)122 << 20));                   // 0.5 MB

  conv_x<<<8192, 256, 0, stream>>>(x, xbf, (B_ * L_ * D_) / 4);
  trans_w<<<dim3(4096 / 64, 1024 / 64), 256, 0, stream>>>(Wqkuv, Wt, 1024, 4096);
  trans_w<<<dim3(1024 / 64, 1024 / 64), 256, 0, stream>>>(Wout, Wot, 1024, 1024);
  rope_tab<<<(L_ * 32) / 256, 256, 0, stream>>>(tab);

  gemm_bf16<1><<<dim3(4096 / 128, 8192 / 128), 256, 0, stream>>>(xbf, Wt, qkuv_bf,
                                                                 B_ * L_, 4 * D_, D_);
  rope_conv<<<dim3(L_ / 64, B_ * H_), 256, 0, stream>>>(qkuv_bf, vt, tab);
  attn_mfma<<<dim3(L_ / 128, B_ * H_), 256, 0, stream>>>(qkuv_bf, vt, amask, cmask, cbias,
                                                         gamma, beta, attng);
  gemm_bf16<0><<<dim3(1024 / 128, 8192 / 128), 256, 0, stream>>>(attng, Wot, out,
                                                                 B_ * L_, D_, D_);
}